// Round 10
// baseline (142.023 us; speedup 1.0000x reference)
//
#include <hip/hip_runtime.h>
#include <hip/hip_bf16.h>
#include <math.h>

#define B_ 4
#define N_ 256
#define D_ 128
#define H_ 256
#define K_ 8

typedef __attribute__((ext_vector_type(8))) short short8;
typedef __attribute__((ext_vector_type(4))) float f32x4;

__device__ __forceinline__ unsigned short f2bf(float x) {
    union { __hip_bfloat16 h; unsigned short s; } u;
    u.h = __float2bfloat16(x);
    return u.s;
}
__device__ __forceinline__ float bf2f(unsigned short b) {
    unsigned v = ((unsigned)b) << 16;
    return __builtin_bit_cast(float, v);
}
__device__ __forceinline__ unsigned pk2(float x, float y) {
    union { __hip_bfloat162 h; unsigned u; } c;
    c.h = __float22bfloat162_rn(float2{x, y});
    return c.u;
}
// async global->LDS, 16 B per lane; no VGPR round-trip
__device__ __forceinline__ void gld_lds16(const float* g, float* l) {
    __builtin_amdgcn_global_load_lds(
        (const __attribute__((address_space(1))) void*)g,
        (__attribute__((address_space(3))) void*)l, 16, 0, 0);
}

// K0 v2 (unchanged, proven).
__global__ __launch_bounds__(256) void pre_kernel(
    const float* __restrict__ s, const float* __restrict__ W1,
    const float* __restrict__ b1,
    float* __restrict__ avec, float* __restrict__ bvec,
    unsigned short* __restrict__ Wt)
{
    int blk = blockIdx.x;
    int t = threadIdx.x;
    if (blk < 512) {
        int bi0 = blk * 2;
        __shared__ float s2[2][D_];
        {
            int r = t >> 7, d = t & 127;
            s2[r][d] = s[(size_t)(bi0 + r) * D_ + d];
        }
        __syncthreads();
        float aA0 = b1[t], aA1 = aA0, aB0 = 0.f, aB1 = 0.f;
        const float* W1a = W1 + t;
        const float* W1b = W1 + (size_t)D_ * H_ + t;
        #pragma unroll 8
        for (int d = 0; d < D_; ++d) {
            float wa = W1a[(size_t)d * H_];
            float wb = W1b[(size_t)d * H_];
            float s0 = s2[0][d], s1 = s2[1][d];
            aA0 = fmaf(s0, wa, aA0);
            aA1 = fmaf(s1, wa, aA1);
            aB0 = fmaf(s0, wb, aB0);
            aB1 = fmaf(s1, wb, aB1);
        }
        avec[(size_t)bi0 * H_ + t]       = aA0;
        avec[(size_t)(bi0 + 1) * H_ + t] = aA1;
        bvec[(size_t)bi0 * H_ + t]       = aB0;
        bvec[(size_t)(bi0 + 1) * H_ + t] = aB1;
    } else {
        int e = (blk - 512) * 256 + t;
        int h = e >> 7, d = e & 127;
        Wt[e] = f2bf(W1[(size_t)(2 * D_ + d) * H_ + h]);
    }
}

// K1 v12: REGISTER-RESIDENT P-fragments — no shared P tile, no round
// barriers. Blocks = b(4) x jt(16: 16 j) x ic(16: 16 i) = 1024. Each lane's
// B-fragment source sj[jtb+l15][dk*32+quad*8..+7] is round-invariant ->
// hoisted to 8 float4 VGPRs; si comes from conflict-free broadcast LDS
// reads; fragment built per round with 8 mul + 4 pk2 per dk. Pl buffer,
// P-build phase and ALL 16 round barriers are gone (2 barriers total);
// per-round h-partials go to write-only LDS partial[8][16][16], reduced
// once at the end. Arithmetic bit-identical to v7 (same pk2 products, MFMA
// order, C-init, reduction order). VGPR ~110 under __launch_bounds__(512,4)
// -> 2 blocks/CU, waves free-run (v7 was 50% dead time, bulk-synchronous).
__global__ __launch_bounds__(512, 4) void approx_scores(
    const float* __restrict__ s, const unsigned short* __restrict__ Wt,
    const float* __restrict__ W2, const float* __restrict__ b2,
    const float* __restrict__ avec, const float* __restrict__ bvec,
    unsigned short* __restrict__ ascu)
{
    int blk = blockIdx.x;              // 1024 = b(4) x jt(16) x ic(16)
    int b   = blk >> 8;
    int jtb = ((blk >> 4) & 15) * 16;
    int i0  = (blk & 15) * 16;
    int t = threadIdx.x;
    int lane = t & 63;
    int w = __builtin_amdgcn_readfirstlane(t >> 6);    // wave 0..7 -> 32-h slice
    int l15 = lane & 15, quad = lane >> 4;

    __shared__ __align__(16) float si_all[16][D_];     // 8 KB
    __shared__ __align__(16) float av_l[16][H_];       // 16 KB (DMA'd avec)
    __shared__ float partial[8][16][16];               // 8 KB (write-only in loop)

    const float* sB = s + (size_t)b * N_ * D_;

    // async DMA: avec rows i0..i0+15 (contiguous 16 KB) -> LDS.
    {
        const float* avp = avec + (size_t)(b * N_ + i0) * H_;
        #pragma unroll
        for (int k = 0; k < 2; ++k) {
            int slot = t + 512 * k;
            gld_lds16(avp + slot * 4, &av_l[0][0] + slot * 4);
        }
    }

    {
        int ii = t >> 5, dq = t & 31;
        *(float4*)&si_all[ii][dq * 4] =
            *(const float4*)(sB + (size_t)(i0 + ii) * D_ + dq * 4);
    }

    short8 Wreg[2][4];
    #pragma unroll
    for (int mi = 0; mi < 2; ++mi)
        #pragma unroll
        for (int dk = 0; dk < 4; ++dk)
            Wreg[mi][dk] = *(const short8*)(
                Wt + (size_t)(w * 32 + mi * 16 + l15) * D_ + dk * 32 + quad * 8);

    // per-lane j = jtb + l15: sj segments (round-invariant, 8 float4)
    float4 sjr[4][2];
    {
        const float* sj = sB + (size_t)(jtb + l15) * D_ + quad * 8;
        #pragma unroll
        for (int dk = 0; dk < 4; ++dk) {
            sjr[dk][0] = ((const float4*)(sj + dk * 32))[0];
            sjr[dk][1] = ((const float4*)(sj + dk * 32))[1];
        }
    }
    // bias for this lane's j, and W2 slice
    float4 bvr[2];
    float w2r[2][4];
    #pragma unroll
    for (int mi = 0; mi < 2; ++mi) {
        int hq = w * 32 + mi * 16 + quad * 4;
        bvr[mi] = *(const float4*)&bvec[((size_t)(b * N_ + jtb + l15)) * H_ + hq];
        #pragma unroll
        for (int r = 0; r < 4; ++r)
            w2r[mi][r] = W2[hq + r];
    }
    float b2v = b2[0];
    __syncthreads();                   // si_all ready + avec DMA drained

    // ---- 16 rounds, NO barriers: waves free-run ----
    #pragma unroll 1
    for (int i = 0; i < 16; ++i) {
        // C-init = a_i[h] + b_j[h] (av broadcast from LDS, bv in regs)
        float4 av0 = *(const float4*)&av_l[i][w * 32 + quad * 4];
        float4 av1 = *(const float4*)&av_l[i][w * 32 + 16 + quad * 4];
        f32x4 acc[2];
        #pragma unroll
        for (int r = 0; r < 4; ++r) {
            acc[0][r] = av0[r] + bvr[0][r];
            acc[1][r] = av1[r] + bvr[1][r];
        }
        #pragma unroll
        for (int dk = 0; dk < 4; ++dk) {
            // si segment (broadcast within quad-group, conflict-free)
            float4 si0 = *(const float4*)&si_all[i][dk * 32 + quad * 8];
            float4 si1 = *(const float4*)&si_all[i][dk * 32 + quad * 8 + 4];
            union { uint4 u; short8 s8; } pf;
            pf.u.x = pk2(sjr[dk][0].x * si0.x, sjr[dk][0].y * si0.y);
            pf.u.y = pk2(sjr[dk][0].z * si0.z, sjr[dk][0].w * si0.w);
            pf.u.z = pk2(sjr[dk][1].x * si1.x, sjr[dk][1].y * si1.y);
            pf.u.w = pk2(sjr[dk][1].z * si1.z, sjr[dk][1].w * si1.w);
            #pragma unroll
            for (int mi = 0; mi < 2; ++mi)
                acc[mi] = __builtin_amdgcn_mfma_f32_16x16x32_bf16(
                    Wreg[mi][dk], pf.s8, acc[mi], 0, 0, 0);
        }
        // epilogue: relu * W2, reduce over this wave's 32 h (4-lane group)
        float rs = 0.f;
        #pragma unroll
        for (int mi = 0; mi < 2; ++mi)
            #pragma unroll
            for (int r = 0; r < 4; ++r)
                rs = fmaf(fmaxf(acc[mi][r], 0.f), w2r[mi][r], rs);
        rs += __shfl_xor(rs, 16);
        rs += __shfl_xor(rs, 32);
        if (lane < 16) partial[w][i][l15] = rs;
    }
    __syncthreads();                   // all partials visible

    // final reduce: 256 threads, one (i,j) each; same ww order as v7
    if (t < 256) {
        int i = t >> 4, j = t & 15;
        float sum = b2v;
        #pragma unroll
        for (int ww = 0; ww < 8; ++ww) sum += partial[ww][i][j];
        ascu[(size_t)(b * N_ + i0 + i) * N_ + jtb + j] = f2bf(sum);
    }
}

// K2 v11 (unchanged from R7: wave-private W staging, barrier-free K-loop).
#define DC8 8
__global__ __launch_bounds__(256) void finalize_kernel(
    const float* __restrict__ s, const float* __restrict__ W1,
    const float* __restrict__ W2, const float* __restrict__ b2,
    const float* __restrict__ avec, const float* __restrict__ bvec,
    const unsigned short* __restrict__ ascu,
    float* __restrict__ ctx, float* __restrict__ gate, float* __restrict__ w)
{
    int bi0 = blockIdx.x * 2;          // 512 blocks, 2 rows each
    int b = bi0 >> 8;
    int t = threadIdx.x;               // 0..255
    int lane = t & 63;
    int wv_id = t >> 6;                // wave 0..3 -> h slice [64w, 64w+64)

    __shared__ float asc[2][N_];                     // 2 KB
    __shared__ int cand[2][16];
    __shared__ __align__(16) float Pt[D_ * 32];      // 16 KB, addr d*32+rr*16+c
    __shared__ __align__(16) float Wlw[4][2][DC8][64]; // 16 KB per-wave dbuf
    __shared__ float part[2][16][33];                // 4.2 KB
    __shared__ float rsc[2][16];
    __shared__ int sel8[2][8];

    // --- load approx scores: 2 per thread ---
    for (int e = t; e < 512; e += 256) {
        int r = e >> 8, jj = e & 255;
        asc[r][jj] = bf2f(ascu[(size_t)(bi0 + r) * N_ + jj]);
    }
    __syncthreads();

    // --- rank-select top-16: 128 threads per row, 2 j's each ---
    {
        int r = t >> 7, lj = t & 127;
        float my[2]; int rk[2];
        #pragma unroll
        for (int m = 0; m < 2; ++m) { my[m] = asc[r][m * 128 + lj]; rk[m] = 0; }
        #pragma unroll 4
        for (int j2 = 0; j2 < N_; ++j2) {
            float o = asc[r][j2];
            #pragma unroll
            for (int m = 0; m < 2; ++m) {
                int jm = m * 128 + lj;
                rk[m] += (o > my[m]) || (o == my[m] && j2 < jm);
            }
        }
        #pragma unroll
        for (int m = 0; m < 2; ++m)
            if (rk[m] < 16) cand[r][rk[m]] = m * 128 + lj;
    }
    __syncthreads();

    const float* Wc = W1 + (size_t)2 * D_ * H_;      // W1c[d][h]

    // per-wave lane mapping for W DMA: lane covers (d_loc, 4 h)
    int dl = lane >> 4;                // 0..3
    int hl = (lane & 15) * 4;          // 0..60

    // issue chunk-0 DMA: wave w stages W1c[0..7][64w .. 64w+63] (2 KB)
    #pragma unroll
    for (int k = 0; k < 2; ++k)
        gld_lds16(Wc + (size_t)(k * 4 + dl) * H_ + wv_id * 64 + hl,
                  &Wlw[wv_id][0][k * 4 + dl][hl]);

    // --- build Pt: Pt[d*32 + rr*16 + c] = s_i[d]*s_j[d] (32 pairs) ---
    for (int e = t; e < 1024; e += 256) {
        int rr = e >> 9, c = e & 15, dq = (e >> 4) & 31;
        int j = cand[rr][c];
        float4 sj = *(const float4*)(s + ((size_t)(b * N_ + j)) * D_ + dq * 4);
        float4 si = *(const float4*)(s + ((size_t)(bi0 + rr)) * D_ + dq * 4);
        int base = (dq * 4) * 32 + rr * 16 + c;
        Pt[base + 0 * 32] = si.x * sj.x;
        Pt[base + 1 * 32] = si.y * sj.y;
        Pt[base + 2 * 32] = si.z * sj.z;
        Pt[base + 3 * 32] = si.w * sj.w;
    }

    // --- acc init: exact fp32 a_i[h] + b_j[h] for 4 cands x 8 h ---
    int cg = t & 3, rr = (t >> 2) & 1;
    int hg = t >> 3;                    // 0..31, 8 h each
    int h0 = hg * 8;
    int ho = (hg & 7) * 8;              // h offset within own wave's 64-h slice
    float acc[4][8];
    {
        const float* av = avec + (size_t)(bi0 + rr) * H_ + h0;
        float4 av40 = *(const float4*)(av);
        float4 av41 = *(const float4*)(av + 4);
        #pragma unroll
        for (int cc = 0; cc < 4; ++cc) {
            int j = cand[rr][cg * 4 + cc];
            const float* bv = bvec + ((size_t)(b * N_ + j)) * H_ + h0;
            float4 b40 = *(const float4*)(bv);
            float4 b41 = *(const float4*)(bv + 4);
            acc[cc][0] = av40.x + b40.x;
            acc[cc][1] = av40.y + b40.y;
            acc[cc][2] = av40.z + b40.z;
            acc[cc][3] = av40.w + b40.w;
            acc[cc][4] = av41.x + b41.x;
            acc[cc][5] = av41.y + b41.y;
            acc[cc][6] = av41.z + b41.z;
            acc[cc][7] = av41.w + b41.w;
        }
    }
    __syncthreads();   // drains chunk-0 DMA (vmcnt(0)) + Pt writes

    // --- K-chunked GEMM, barrier-free: per-wave DMA + counted vmcnt ---
    int pvoff = rr * 16 + cg * 4;
    #pragma unroll 1
    for (int ch = 0; ch < 15; ++ch) {
        int cur = ch & 1;
        // issue chunk ch+1 into other half (wave-private)
        {
            const float* src = Wc + (size_t)((ch + 1) * DC8) * H_;
            #pragma unroll
            for (int k = 0; k < 2; ++k)
                gld_lds16(src + (size_t)(k * 4 + dl) * H_ + wv_id * 64 + hl,
                          &Wlw[wv_id][cur ^ 1][k * 4 + dl][hl]);
        }
        // chunk ch's 2 DMAs are the oldest outstanding -> wait them only
        asm volatile("s_waitcnt vmcnt(2)" ::: "memory");
        __builtin_amdgcn_sched_barrier(0);
        int d0 = ch * DC8;
        #pragma unroll
        for (int d = 0; d < DC8; ++d) {
            float4 pv = *(const float4*)&Pt[(d0 + d) * 32 + pvoff];
            float wvv[8];
            *(float4*)&wvv[0] = *(const float4*)&Wlw[wv_id][cur][d][ho];
            *(float4*)&wvv[4] = *(const float4*)&Wlw[wv_id][cur][d][ho + 4];
            #pragma unroll
            for (int m = 0; m < 8; ++m) {
                acc[0][m] = fmaf(pv.x, wvv[m], acc[0][m]);
                acc[1][m] = fmaf(pv.y, wvv[m], acc[1][m]);
                acc[2][m] = fmaf(pv.z, wvv[m], acc[2][m]);
                acc[3][m] = fmaf(pv.w, wvv[m], acc[3][m]);
            }
        }
    }
    // last chunk (15): nothing left to issue; drain own DMAs
    asm volatile("s_waitcnt vmcnt(0)" ::: "memory");
    __builtin_amdgcn_sched_barrier(0);
    {
        int d0 = 15 * DC8;
        #pragma unroll
        for (int d = 0; d < DC8; ++d) {
            float4 pv = *(const float4*)&Pt[(d0 + d) * 32 + pvoff];
            float wvv[8];
            *(float4*)&wvv[0] = *(const float4*)&Wlw[wv_id][1][d][ho];
            *(float4*)&wvv[4] = *(const float4*)&Wlw[wv_id][1][d][ho + 4];
            #pragma unroll
            for (int m = 0; m < 8; ++m) {
                acc[0][m] = fmaf(pv.x, wvv[m], acc[0][m]);
                acc[1][m] = fmaf(pv.y, wvv[m], acc[1][m]);
                acc[2][m] = fmaf(pv.z, wvv[m], acc[2][m]);
                acc[3][m] = fmaf(pv.w, wvv[m], acc[3][m]);
            }
        }
    }

    // --- epilogue: relu * W2 partial per (r, cand), reduce over 32 hg ---
    {
        float w2v[8];
        *(float4*)&w2v[0] = *(const float4*)(W2 + h0);
        *(float4*)&w2v[4] = *(const float4*)(W2 + h0 + 4);
        #pragma unroll
        for (int cc = 0; cc < 4; ++cc) {
            float sc = 0.f;
            #pragma unroll
            for (int m = 0; m < 8; ++m)
                sc = fmaf(fmaxf(acc[cc][m], 0.f), w2v[m], sc);
            part[rr][cg * 4 + cc][hg] = sc;
        }
    }
    __syncthreads();
    if (t < 32) {
        int r2 = t >> 4, c2 = t & 15;
        float sum = b2[0];
        #pragma unroll
        for (int m = 0; m < 32; ++m) sum += part[r2][c2][m];
        rsc[r2][c2] = sum;
    }
    __syncthreads();

    // top-8 among 16 exact scores, tiebreak smaller original index
    if (t < 32) {
        int r2 = t >> 4, c2 = t & 15;
        float my = rsc[r2][c2]; int myj = cand[r2][c2];
        int rank = 0;
        #pragma unroll
        for (int c3 = 0; c3 < 16; ++c3) {
            float o = rsc[r2][c3]; int oj = cand[r2][c3];
            rank += (o > my) || (o == my && oj < myj);
        }
        if (rank < 8) sel8[r2][rank] = myj;
    }
    __syncthreads();

    // gate / w: 2 rows x 256 j, 2 per thread
    for (int e = t; e < 512; e += 256) {
        int r2 = e >> 8, jj = e & 255;
        float gv = 0.f;
        #pragma unroll
        for (int m = 0; m < 8; ++m)
            gv = (jj == sel8[r2][m]) ? 1.f : gv;
        gate[(size_t)(bi0 + r2) * N_ + jj] = gv;
        w[(size_t)(bi0 + r2) * N_ + jj]    = gv * 0.125f;
    }
    // ctx: 2 rows x 128 d, 1 per thread
    {
        int r2 = t >> 7, d = t & 127;
        float a = 0.f;
        #pragma unroll
        for (int m = 0; m < 8; ++m)
            a += s[((size_t)(b * N_ + sel8[r2][m])) * D_ + d];
        ctx[(size_t)(bi0 + r2) * D_ + d] = a * 0.125f;
    }
}

extern "C" void kernel_launch(void* const* d_in, const int* in_sizes, int n_in,
                              void* d_out, int out_size, void* d_ws, size_t ws_size,
                              hipStream_t stream)
{
    const float* s  = (const float*)d_in[0];
    const float* W1 = (const float*)d_in[1];
    const float* b1 = (const float*)d_in[2];
    const float* W2 = (const float*)d_in[3];
    const float* b2 = (const float*)d_in[4];

    float* avec = (float*)d_ws;                                           // 262144 f
    float* bvec = avec + (size_t)B_ * N_ * H_;                            // 262144 f
    unsigned short* ascu = (unsigned short*)(bvec + (size_t)B_ * N_ * H_);// 262144 us
    unsigned short* Wtu  = ascu + (size_t)B_ * N_ * N_;                   // 32768 us

    float* ctx  = (float*)d_out;
    float* gate = ctx + (size_t)B_ * N_ * D_;
    float* wout = gate + (size_t)B_ * N_ * N_;

    pre_kernel<<<640, 256, 0, stream>>>(s, W1, b1, avec, bvec, Wtu);
    approx_scores<<<1024, 512, 0, stream>>>(s, Wtu, W2, b2, avec, bvec, ascu);
    finalize_kernel<<<B_ * N_ / 2, 256, 0, stream>>>(s, W1, W2, b2, avec, bvec, ascu,
                                                     ctx, gate, wout);
}

// Round 12
// 124.400 us; speedup vs baseline: 1.1417x; 1.1417x over previous
//
#include <hip/hip_runtime.h>
#include <hip/hip_bf16.h>
#include <math.h>

#define B_ 4
#define N_ 256
#define D_ 128
#define H_ 256
#define K_ 8

typedef __attribute__((ext_vector_type(8))) short short8;
typedef __attribute__((ext_vector_type(4))) float f32x4;

__device__ __forceinline__ unsigned short f2bf(float x) {
    union { __hip_bfloat16 h; unsigned short s; } u;
    u.h = __float2bfloat16(x);
    return u.s;
}
__device__ __forceinline__ float bf2f(unsigned short b) {
    unsigned v = ((unsigned)b) << 16;
    return __builtin_bit_cast(float, v);
}
__device__ __forceinline__ unsigned pk2(float x, float y) {
    union { __hip_bfloat162 h; unsigned u; } c;
    c.h = __float22bfloat162_rn(float2{x, y});
    return c.u;
}
// async global->LDS, 16 B per lane; no VGPR round-trip
__device__ __forceinline__ void gld_lds16(const float* g, float* l) {
    __builtin_amdgcn_global_load_lds(
        (const __attribute__((address_space(1))) void*)g,
        (__attribute__((address_space(3))) void*)l, 16, 0, 0);
}

// K0 v2 (unchanged, proven).
__global__ __launch_bounds__(256) void pre_kernel(
    const float* __restrict__ s, const float* __restrict__ W1,
    const float* __restrict__ b1,
    float* __restrict__ avec, float* __restrict__ bvec,
    unsigned short* __restrict__ Wt)
{
    int blk = blockIdx.x;
    int t = threadIdx.x;
    if (blk < 512) {
        int bi0 = blk * 2;
        __shared__ float s2[2][D_];
        {
            int r = t >> 7, d = t & 127;
            s2[r][d] = s[(size_t)(bi0 + r) * D_ + d];
        }
        __syncthreads();
        float aA0 = b1[t], aA1 = aA0, aB0 = 0.f, aB1 = 0.f;
        const float* W1a = W1 + t;
        const float* W1b = W1 + (size_t)D_ * H_ + t;
        #pragma unroll 8
        for (int d = 0; d < D_; ++d) {
            float wa = W1a[(size_t)d * H_];
            float wb = W1b[(size_t)d * H_];
            float s0 = s2[0][d], s1 = s2[1][d];
            aA0 = fmaf(s0, wa, aA0);
            aA1 = fmaf(s1, wa, aA1);
            aB0 = fmaf(s0, wb, aB0);
            aB1 = fmaf(s1, wb, aB1);
        }
        avec[(size_t)bi0 * H_ + t]       = aA0;
        avec[(size_t)(bi0 + 1) * H_ + t] = aA1;
        bvec[(size_t)bi0 * H_ + t]       = aB0;
        bvec[(size_t)(bi0 + 1) * H_ + t] = aB1;
    } else {
        int e = (blk - 512) * 256 + t;
        int h = e >> 7, d = e & 127;
        Wt[e] = f2bf(W1[(size_t)(2 * D_ + d) * H_ + h]);
    }
}

// K1 v7 (R1/R7, proven best: shared P-build = 1x VALU; 512 blocks, 16 rounds).
__global__ __launch_bounds__(512, 2) void approx_scores(
    const float* __restrict__ s, const unsigned short* __restrict__ Wt,
    const float* __restrict__ W2, const float* __restrict__ b2,
    const float* __restrict__ avec, const float* __restrict__ bvec,
    unsigned short* __restrict__ ascu)
{
    int blk = blockIdx.x;              // 512 = b(4) x jt(8) x ic(16)
    int b   = blk >> 7;
    int jtb = ((blk >> 4) & 7) * 32;
    int i0  = (blk & 15) * 16;
    int t = threadIdx.x;
    int lane = t & 63;
    int w = __builtin_amdgcn_readfirstlane(t >> 6);    // wave 0..7 -> 32-h slice
    int l15 = lane & 15, quad = lane >> 4;

    __shared__ __align__(16) short Pl[2][32 * 128];    // 16 KB (dbuf)
    __shared__ __align__(16) float si_all[16][D_];     // 8 KB
    __shared__ __align__(16) float av_l[16][H_];       // 16 KB (DMA'd avec slice)
    __shared__ float partial[2][8][32];                // 2 KB

    const float* sB = s + (size_t)b * N_ * D_;

    // async DMA: avec rows i0..i0+15 (contiguous 16 KB) -> LDS.
    {
        const float* avp = avec + (size_t)(b * N_ + i0) * H_;
        #pragma unroll
        for (int k = 0; k < 2; ++k) {
            int slot = t + 512 * k;
            gld_lds16(avp + slot * 4, &av_l[0][0] + slot * 4);
        }
    }

    {
        int ii = t >> 5, dq = t & 31;
        *(float4*)&si_all[ii][dq * 4] =
            *(const float4*)(sB + (size_t)(i0 + ii) * D_ + dq * 4);
    }

    short8 Wreg[2][4];
    #pragma unroll
    for (int mi = 0; mi < 2; ++mi)
        #pragma unroll
        for (int dk = 0; dk < 4; ++dk)
            Wreg[mi][dk] = *(const short8*)(
                Wt + (size_t)(w * 32 + mi * 16 + l15) * D_ + dk * 32 + quad * 8);
    float bvr[2][2][4];
    float w2r[2][4];
    #pragma unroll
    for (int mi = 0; mi < 2; ++mi) {
        int hq = w * 32 + mi * 16 + quad * 4;
        #pragma unroll
        for (int r = 0; r < 4; ++r)
            w2r[mi][r] = W2[hq + r];
        #pragma unroll
        for (int nj = 0; nj < 2; ++nj)
            #pragma unroll
            for (int r = 0; r < 4; ++r)
                bvr[mi][nj][r] = bvec[((size_t)(b * N_ + jtb + nj * 16 + l15)) * H_
                                      + hq + r];
    }
    float b2v = b2[0];

    // loop-invariant sj pair
    int prow = t >> 4, pseg = t & 15;
    float4 sj0, sj1;
    {
        const float* sj = sB + (size_t)(jtb + prow) * D_ + pseg * 8;
        sj0 = ((const float4*)sj)[0];
        sj1 = ((const float4*)sj)[1];
    }
    __syncthreads();                   // si_all ready + avec DMA drained

    {
        const float* si = &si_all[0][pseg * 8];
        float4 s0 = ((const float4*)si)[0], s1 = ((const float4*)si)[1];
        uint4 v;
        v.x = pk2(sj0.x * s0.x, sj0.y * s0.y);
        v.y = pk2(sj0.z * s0.z, sj0.w * s0.w);
        v.z = pk2(sj1.x * s1.x, sj1.y * s1.y);
        v.w = pk2(sj1.z * s1.z, sj1.w * s1.w);
        int pc = pseg ^ (prow & 15);
        *(uint4*)&Pl[0][prow * 128 + pc * 8] = v;
    }
    __syncthreads();

    #pragma unroll 1
    for (int i = 0; i < 16; ++i) {
        int cur = i & 1;
        if (w == 0 && lane < 32 && i > 0) {
            float sum = b2v;
            #pragma unroll
            for (int ww = 0; ww < 8; ++ww) sum += partial[(i - 1) & 1][ww][lane];
            ascu[(size_t)(b * N_ + i0 + i - 1) * N_ + jtb + lane] = f2bf(sum);
        }
        float4 av4[2];
        av4[0] = *(const float4*)&av_l[i][w * 32 + quad * 4];
        av4[1] = *(const float4*)&av_l[i][w * 32 + 16 + quad * 4];
        f32x4 acc[2][2];
        #pragma unroll
        for (int mi = 0; mi < 2; ++mi)
            #pragma unroll
            for (int nj = 0; nj < 2; ++nj)
                #pragma unroll
                for (int r = 0; r < 4; ++r)
                    acc[mi][nj][r] = av4[mi][r] + bvr[mi][nj][r];
        #pragma unroll
        for (int dk = 0; dk < 4; ++dk) {
            short8 Pf[2];
            #pragma unroll
            for (int nj = 0; nj < 2; ++nj) {
                int pcc = (dk * 4 + quad) ^ l15;
                Pf[nj] = *(const short8*)&Pl[cur][(nj * 16 + l15) * 128 + pcc * 8];
            }
            #pragma unroll
            for (int nj = 0; nj < 2; ++nj)
                #pragma unroll
                for (int mi = 0; mi < 2; ++mi)
                    acc[mi][nj] = __builtin_amdgcn_mfma_f32_16x16x32_bf16(
                        Wreg[mi][dk], Pf[nj], acc[mi][nj], 0, 0, 0);
        }
        if (i < 15) {
            const float* si = &si_all[i + 1][pseg * 8];
            float4 s0 = ((const float4*)si)[0], s1 = ((const float4*)si)[1];
            uint4 v;
            v.x = pk2(sj0.x * s0.x, sj0.y * s0.y);
            v.y = pk2(sj0.z * s0.z, sj0.w * s0.w);
            v.z = pk2(sj1.x * s1.x, sj1.y * s1.y);
            v.w = pk2(sj1.z * s1.z, sj1.w * s1.w);
            int pc = pseg ^ (prow & 15);
            *(uint4*)&Pl[cur ^ 1][prow * 128 + pc * 8] = v;
        }
        float rs[2];
        rs[0] = 0.f; rs[1] = 0.f;
        #pragma unroll
        for (int mi = 0; mi < 2; ++mi)
            #pragma unroll
            for (int nj = 0; nj < 2; ++nj)
                #pragma unroll
                for (int r = 0; r < 4; ++r)
                    rs[nj] = fmaf(fmaxf(acc[mi][nj][r], 0.f), w2r[mi][r], rs[nj]);
        #pragma unroll
        for (int nj = 0; nj < 2; ++nj) {
            rs[nj] += __shfl_xor(rs[nj], 16);
            rs[nj] += __shfl_xor(rs[nj], 32);
        }
        if (lane < 32) {
            float v = (quad == 0) ? rs[0] : rs[1];
            partial[cur][w][lane] = v;
        }
        __syncthreads();
    }
    if (w == 0 && lane < 32) {
        float sum = b2v;
        #pragma unroll
        for (int ww = 0; ww < 8; ++ww) sum += partial[15 & 1][ww][lane];
        ascu[(size_t)(b * N_ + i0 + 15) * N_ + jtb + lane] = f2bf(sum);
    }
}

// K2 v12: 512 THREADS (v11 was 256 -> only 8 waves/CU, 25% occupancy, for a
// 16-chunk serial DMA chain). 512 blocks x 512 thr = 16 waves/CU (50%).
// Thread = (cg2: 2 cands, rr, hg: 8 h); wave w owns h slice [32w, 32w+32):
// per chunk each wave stages its [8d][32h] slice with EXACTLY 1
// global_load_lds per lane, counted vmcnt(1), barrier-free K-loop (proven
// v11 scheme). Mapping reuses R3 phase-C (passed) + v11 DMA (passed).
#define DC8 8
__global__ __launch_bounds__(512) void finalize_kernel(
    const float* __restrict__ s, const float* __restrict__ W1,
    const float* __restrict__ W2, const float* __restrict__ b2,
    const float* __restrict__ avec, const float* __restrict__ bvec,
    const unsigned short* __restrict__ ascu,
    float* __restrict__ ctx, float* __restrict__ gate, float* __restrict__ w)
{
    int bi0 = blockIdx.x * 2;          // 512 blocks, 2 rows each
    int b = bi0 >> 8;
    int t = threadIdx.x;               // 0..511
    int lane = t & 63;
    int wv = t >> 6;                   // wave 0..7 -> h slice [32w, 32w+32)

    __shared__ float asc[2][N_];                     // 2 KB
    __shared__ int cand[2][16];
    __shared__ __align__(16) float Pt[D_ * 32];      // 16 KB, addr d*32+rr*16+c
    __shared__ __align__(16) float Wlw[8][2][DC8][32]; // 16 KB per-wave dbuf
    __shared__ float partW[8][2][16];                // 1 KB
    __shared__ float rsc[2][16];
    __shared__ int sel8[2][8];

    // --- load approx scores: 1 per thread ---
    {
        int r = t >> 8, jj = t & 255;
        asc[r][jj] = bf2f(ascu[(size_t)(bi0 + r) * N_ + jj]);
    }
    __syncthreads();

    // --- rank-select top-16: 1 j per thread ---
    {
        int r = t >> 8, lj = t & 255;
        float my = asc[r][lj]; int rk = 0;
        #pragma unroll 4
        for (int j2 = 0; j2 < N_; ++j2) {
            float o = asc[r][j2];
            rk += (o > my) || (o == my && j2 < lj);
        }
        if (rk < 16) cand[r][rk] = lj;
    }
    __syncthreads();

    const float* Wc = W1 + (size_t)2 * D_ * H_;      // W1c[d][h]

    // per-wave lane mapping for W DMA: lane covers (d = l>>3, 4 h)
    int dl = lane >> 3;                // 0..7
    int hl = (lane & 7) * 4;           // 0..28

    // issue chunk-0 DMA: wave w stages W1c[0..7][32w .. 32w+31] (1 KB, 1/lane)
    gld_lds16(Wc + (size_t)dl * H_ + wv * 32 + hl, &Wlw[wv][0][dl][hl]);

    // --- build Pt: Pt[d*32 + rr*16 + c] = s_i[d]*s_j[d] (32 pairs) ---
    for (int e = t; e < 1024; e += 512) {
        int rr = e >> 9, c = e & 15, dq = (e >> 4) & 31;
        int j = cand[rr][c];
        float4 sj = *(const float4*)(s + ((size_t)(b * N_ + j)) * D_ + dq * 4);
        float4 si = *(const float4*)(s + ((size_t)(bi0 + rr)) * D_ + dq * 4);
        int base = (dq * 4) * 32 + rr * 16 + c;
        Pt[base + 0 * 32] = si.x * sj.x;
        Pt[base + 1 * 32] = si.y * sj.y;
        Pt[base + 2 * 32] = si.z * sj.z;
        Pt[base + 3 * 32] = si.w * sj.w;
    }

    // --- acc init: exact fp32 a_i[h] + b_j[h] for 2 cands x 8 h ---
    int cg2 = t & 7, rr = (t >> 3) & 1, hg = t >> 4;   // hg 0..31
    int h0 = hg * 8;
    int ho = (hg & 3) * 8;              // h offset within wave's 32-h slice
    float acc[2][8];
    {
        const float* av = avec + (size_t)(bi0 + rr) * H_ + h0;
        float4 av40 = *(const float4*)(av);
        float4 av41 = *(const float4*)(av + 4);
        #pragma unroll
        for (int cc = 0; cc < 2; ++cc) {
            int j = cand[rr][cg2 * 2 + cc];
            const float* bv = bvec + ((size_t)(b * N_ + j)) * H_ + h0;
            float4 b40 = *(const float4*)(bv);
            float4 b41 = *(const float4*)(bv + 4);
            acc[cc][0] = av40.x + b40.x;
            acc[cc][1] = av40.y + b40.y;
            acc[cc][2] = av40.z + b40.z;
            acc[cc][3] = av40.w + b40.w;
            acc[cc][4] = av41.x + b41.x;
            acc[cc][5] = av41.y + b41.y;
            acc[cc][6] = av41.z + b41.z;
            acc[cc][7] = av41.w + b41.w;
        }
    }
    __syncthreads();   // drains chunk-0 DMA (vmcnt(0)) + Pt writes

    // --- K-chunked GEMM, barrier-free: per-wave DMA + counted vmcnt ---
    int pvoff = rr * 16 + cg2 * 2;
    #pragma unroll 1
    for (int ch = 0; ch < 15; ++ch) {
        int cur = ch & 1;
        // issue chunk ch+1 into other half (wave-private, 1 DMA/lane)
        gld_lds16(Wc + (size_t)((ch + 1) * DC8 + dl) * H_ + wv * 32 + hl,
                  &Wlw[wv][cur ^ 1][dl][hl]);
        // chunk ch's DMA is the oldest outstanding -> wait it only
        asm volatile("s_waitcnt vmcnt(1)" ::: "memory");
        __builtin_amdgcn_sched_barrier(0);
        int d0 = ch * DC8;
        #pragma unroll
        for (int d = 0; d < DC8; ++d) {
            float2 pv = *(const float2*)&Pt[(d0 + d) * 32 + pvoff];
            float wvv[8];
            *(float4*)&wvv[0] = *(const float4*)&Wlw[wv][cur][d][ho];
            *(float4*)&wvv[4] = *(const float4*)&Wlw[wv][cur][d][ho + 4];
            #pragma unroll
            for (int m = 0; m < 8; ++m) {
                acc[0][m] = fmaf(pv.x, wvv[m], acc[0][m]);
                acc[1][m] = fmaf(pv.y, wvv[m], acc[1][m]);
            }
        }
    }
    // last chunk (15): nothing left to issue; drain own DMA
    asm volatile("s_waitcnt vmcnt(0)" ::: "memory");
    __builtin_amdgcn_sched_barrier(0);
    {
        int d0 = 15 * DC8;
        #pragma unroll
        for (int d = 0; d < DC8; ++d) {
            float2 pv = *(const float2*)&Pt[(d0 + d) * 32 + pvoff];
            float wvv[8];
            *(float4*)&wvv[0] = *(const float4*)&Wlw[wv][1][d][ho];
            *(float4*)&wvv[4] = *(const float4*)&Wlw[wv][1][d][ho + 4];
            #pragma unroll
            for (int m = 0; m < 8; ++m) {
                acc[0][m] = fmaf(pv.x, wvv[m], acc[0][m]);
                acc[1][m] = fmaf(pv.y, wvv[m], acc[1][m]);
            }
        }
    }

    // --- epilogue: relu * W2, shuffle-reduce over this wave's 4 hg ---
    {
        float w2v[8];
        *(float4*)&w2v[0] = *(const float4*)(W2 + h0);
        *(float4*)&w2v[4] = *(const float4*)(W2 + h0 + 4);
        #pragma unroll
        for (int cc = 0; cc < 2; ++cc) {
            float sc = 0.f;
            #pragma unroll
            for (int m = 0; m < 8; ++m)
                sc = fmaf(fmaxf(acc[cc][m], 0.f), w2v[m], sc);
            sc += __shfl_xor(sc, 16);
            sc += __shfl_xor(sc, 32);
            if (lane < 16) partW[wv][rr][cg2 * 2 + cc] = sc;
        }
    }
    __syncthreads();
    if (t < 32) {
        int r2 = t >> 4, c2 = t & 15;
        float sum = b2[0];
        #pragma unroll
        for (int wv2 = 0; wv2 < 8; ++wv2) sum += partW[wv2][r2][c2];
        rsc[r2][c2] = sum;
    }
    __syncthreads();

    // top-8 among 16 exact scores, tiebreak smaller original index
    if (t < 32) {
        int r2 = t >> 4, c2 = t & 15;
        float my = rsc[r2][c2]; int myj = cand[r2][c2];
        int rank = 0;
        #pragma unroll
        for (int c3 = 0; c3 < 16; ++c3) {
            float o = rsc[r2][c3]; int oj = cand[r2][c3];
            rank += (o > my) || (o == my && oj < myj);
        }
        if (rank < 8) sel8[r2][rank] = myj;
    }
    __syncthreads();

    // gate / w: 1 per thread
    {
        int r2 = t >> 8, jj = t & 255;
        float gv = 0.f;
        #pragma unroll
        for (int m = 0; m < 8; ++m)
            gv = (jj == sel8[r2][m]) ? 1.f : gv;
        gate[(size_t)(bi0 + r2) * N_ + jj] = gv;
        w[(size_t)(bi0 + r2) * N_ + jj]    = gv * 0.125f;
    }
    // ctx: 2 rows x 128 d
    if (t < 256) {
        int r2 = t >> 7, d = t & 127;
        float a = 0.f;
        #pragma unroll
        for (int m = 0; m < 8; ++m)
            a += s[((size_t)(b * N_ + sel8[r2][m])) * D_ + d];
        ctx[(size_t)(bi0 + r2) * D_ + d] = a * 0.125f;
    }
}

extern "C" void kernel_launch(void* const* d_in, const int* in_sizes, int n_in,
                              void* d_out, int out_size, void* d_ws, size_t ws_size,
                              hipStream_t stream)
{
    const float* s  = (const float*)d_in[0];
    const float* W1 = (const float*)d_in[1];
    const float* b1 = (const float*)d_in[2];
    const float* W2 = (const float*)d_in[3];
    const float* b2 = (const float*)d_in[4];

    float* avec = (float*)d_ws;                                           // 262144 f
    float* bvec = avec + (size_t)B_ * N_ * H_;                            // 262144 f
    unsigned short* ascu = (unsigned short*)(bvec + (size_t)B_ * N_ * H_);// 262144 us
    unsigned short* Wtu  = ascu + (size_t)B_ * N_ * N_;                   // 32768 us

    float* ctx  = (float*)d_out;
    float* gate = ctx + (size_t)B_ * N_ * D_;
    float* wout = gate + (size_t)B_ * N_ * N_;

    pre_kernel<<<640, 256, 0, stream>>>(s, W1, b1, avec, bvec, Wtu);
    approx_scores<<<512, 512, 0, stream>>>(s, Wtu, W2, b2, avec, bvec, ascu);
    finalize_kernel<<<B_ * N_ / 2, 512, 0, stream>>>(s, W1, W2, b2, avec, bvec, ascu,
                                                     ctx, gate, wout);
}